// Round 2
// baseline (521.975 us; speedup 1.0000x reference)
//
#include <hip/hip_runtime.h>
#include <hip/hip_bf16.h>
#include <math.h>

#define NTOK    16384
#define DMODEL  1024
#define HN      4
#define NBUCKET 4096
#define ASSOC   4
#define DKEY    64
#define DVAL    128
#define DTAG    32
#define NBITS   12
#define EPSV    1e-6f

// ---------------- generic C[M,N] = A[M,K] * B[N,K]^T (fp32) ----------------
__global__ __launch_bounds__(256) void gemm_tn(const float* __restrict__ A,
                                               const float* __restrict__ Bw,
                                               float* __restrict__ C,
                                               int M, int Ncols, int K) {
    __shared__ __align__(16) float As[32][68];
    __shared__ __align__(16) float Bs[32][68];
    const int bm = blockIdx.x * 64;
    const int bn = blockIdx.y * 64;
    const int tx = threadIdx.x & 15;
    const int ty = threadIdx.x >> 4;
    const int r  = threadIdx.x >> 2;        // 0..63
    const int c  = (threadIdx.x & 3) * 8;   // 0,8,16,24
    float acc[4][4] = {};
    for (int k0 = 0; k0 < K; k0 += 32) {
        const float* srcA = A  + (size_t)(bm + r) * K + (k0 + c);
        const float* srcB = Bw + (size_t)(bn + r) * K + (k0 + c);
        const float4 a0 = *(const float4*)(srcA);
        const float4 a1 = *(const float4*)(srcA + 4);
        const float4 b0 = *(const float4*)(srcB);
        const float4 b1 = *(const float4*)(srcB + 4);
        As[c + 0][r] = a0.x; As[c + 1][r] = a0.y; As[c + 2][r] = a0.z; As[c + 3][r] = a0.w;
        As[c + 4][r] = a1.x; As[c + 5][r] = a1.y; As[c + 6][r] = a1.z; As[c + 7][r] = a1.w;
        Bs[c + 0][r] = b0.x; Bs[c + 1][r] = b0.y; Bs[c + 2][r] = b0.z; Bs[c + 3][r] = b0.w;
        Bs[c + 4][r] = b1.x; Bs[c + 5][r] = b1.y; Bs[c + 6][r] = b1.z; Bs[c + 7][r] = b1.w;
        __syncthreads();
        #pragma unroll
        for (int kk = 0; kk < 32; ++kk) {
            const float4 av = *(const float4*)&As[kk][ty * 4];
            const float4 bv = *(const float4*)&Bs[kk][tx * 4];
            const float a[4] = {av.x, av.y, av.z, av.w};
            const float b[4] = {bv.x, bv.y, bv.z, bv.w};
            #pragma unroll
            for (int i = 0; i < 4; ++i)
                #pragma unroll
                for (int j = 0; j < 4; ++j)
                    acc[i][j] = fmaf(a[i], b[j], acc[i][j]);
        }
        __syncthreads();
    }
    #pragma unroll
    for (int i = 0; i < 4; ++i)
        #pragma unroll
        for (int j = 0; j < 4; ++j)
            C[(size_t)(bm + ty * 4 + i) * Ncols + (bn + tx * 4 + j)] = acc[i][j];
}

// ---------------- gate = sigmoid(u . Wg + bg) ----------------
__global__ __launch_bounds__(256) void gate_kernel(const float* __restrict__ u,
                                                   const float* __restrict__ Wg,
                                                   const float* __restrict__ bg,
                                                   float* __restrict__ gateg) {
    const int wv = threadIdx.x >> 6, lane = threadIdx.x & 63;
    const int n = blockIdx.x * 4 + wv;
    const float* up = u + (size_t)n * DMODEL;
    float acc = 0.f;
    #pragma unroll
    for (int j = 0; j < 16; ++j)
        acc += up[lane + 64 * j] * Wg[lane + 64 * j];
    #pragma unroll
    for (int off = 1; off < 64; off <<= 1) acc += __shfl_xor(acc, off);
    if (lane == 0) gateg[n] = 1.f / (1.f + expf(-(acc + bg[0])));
}

// ---------------- fused routing / gather / score / read / scatter ----------------
// one wave per token, 4 waves per block
__global__ __launch_bounds__(256) void route_kernel(
    const float* __restrict__ memK, const float* __restrict__ memV,
    const float* __restrict__ memT, const float* __restrict__ R,
    const float* __restrict__ Wvsa,
    const float* __restrict__ qkeyg, const float* __restrict__ wkeyg,
    const float* __restrict__ wvalg, const float* __restrict__ gateg,
    float* __restrict__ accK, float* __restrict__ accV, float* __restrict__ accT,
    float* __restrict__ readw) {
    __shared__ float sQK[4][64], sWK[4][64], sQT[4][32], sWT[4][32];
    __shared__ float sSc[4][16], sSim[4][16], sTsim[4][16], sW[4][16];
    __shared__ int   sIdx[4][4], sAst[4][4];
    __shared__ float sEff[4][4];

    const int wv = threadIdx.x >> 6;
    const int lane = threadIdx.x & 63;
    const int n = blockIdx.x * 4 + wv;

    // stage projections in LDS; wkey norm via butterfly
    const float qk = qkeyg[(size_t)n * DKEY + lane];
    const float wk = wkeyg[(size_t)n * DKEY + lane];
    sQK[wv][lane] = qk;
    sWK[wv][lane] = wk;
    float wk2 = wk * wk;
    #pragma unroll
    for (int off = 1; off < 64; off <<= 1) wk2 += __shfl_xor(wk2, off);
    const float wknorm = sqrtf(wk2) + EPSV;
    __syncthreads();

    // qtag (lanes 0..31) / wtag (lanes 32..63): tanh(key . Wvsa)
    {
        const int t = lane & 31;
        const float* keyp = (lane < 32) ? sQK[wv] : sWK[wv];
        float tacc = 0.f;
        for (int d = 0; d < 64; ++d) tacc += keyp[d] * Wvsa[d * DTAG + t];
        const float tagv = tanhf(tacc);
        if (lane < 32) sQT[wv][t] = tagv; else sWT[wv][t] = tagv;
        float wt2 = (lane >= 32) ? tagv * tagv : 0.f;
        #pragma unroll
        for (int off = 1; off < 64; off <<= 1) wt2 += __shfl_xor(wt2, off);
        const float wtnorm = sqrtf(wt2) + EPSV;

        // routing bits: lane -> (h = lane/12, k = lane%12), idx via ballot
        bool bit = false;
        if (lane < 48) {
            const int h = lane / 12, k = lane % 12;
            float bacc = 0.f;
            for (int d = 0; d < 64; ++d)
                bacc += sQK[wv][d] * R[(size_t)(h * DKEY + d) * NBITS + k];
            bit = bacc > 0.f;
        }
        const unsigned long long mask = __ballot(bit);
        if (lane < 4) sIdx[wv][lane] = (int)((mask >> (12 * lane)) & 0xFFFull);
        __syncthreads();

        // per-slot reductions: 4 lanes per slot (16 slots = H*A)
        const int slot = lane >> 2, sub = lane & 3;
        const int sh = slot >> 2, sa = slot & 3;
        const int rowS = (sh * NBUCKET + sIdx[wv][sh]) * ASSOC + sa;
        const float* Kp = memK + (size_t)rowS * DKEY;
        const float* Tp = memT + (size_t)rowS * DTAG;
        float d_qk = 0, d_wk = 0, d_kk = 0, d_qt = 0, d_wt = 0, d_tt = 0;
        for (int j = 0; j < 16; ++j) {
            const int d = sub * 16 + j;
            const float kv = Kp[d];
            d_qk += sQK[wv][d] * kv;
            d_wk += sWK[wv][d] * kv;
            d_kk += kv * kv;
        }
        for (int j = 0; j < 8; ++j) {
            const int d = sub * 8 + j;
            const float tv = Tp[d];
            d_qt += sQT[wv][d] * tv;
            d_wt += sWT[wv][d] * tv;
            d_tt += tv * tv;
        }
        #pragma unroll
        for (int off = 1; off <= 2; off <<= 1) {
            d_qk += __shfl_xor(d_qk, off);
            d_wk += __shfl_xor(d_wk, off);
            d_kk += __shfl_xor(d_kk, off);
            d_qt += __shfl_xor(d_qt, off);
            d_wt += __shfl_xor(d_wt, off);
            d_tt += __shfl_xor(d_tt, off);
        }
        if (sub == 0) {
            sSc[wv][slot]   = d_qk * 0.125f + d_qt * 0.17677669529663687f; // /sqrt(64), /sqrt(32)
            sSim[wv][slot]  = d_wk / (wknorm * (sqrtf(d_kk) + EPSV));
            sTsim[wv][slot] = d_wt / (wtnorm * (sqrtf(d_tt) + EPSV));
        }
    }
    __syncthreads();

    // softmax over 16 slots (lanes 0..15)
    if (lane < 16) {
        const float sc = sSc[wv][lane];
        float m = sc;
        #pragma unroll
        for (int off = 1; off < 16; off <<= 1) m = fmaxf(m, __shfl_xor(m, off, 16));
        const float e = expf(sc - m);
        float ssum = e;
        #pragma unroll
        for (int off = 1; off < 16; off <<= 1) ssum += __shfl_xor(ssum, off, 16);
        sW[wv][lane] = e / ssum;
    }
    // per-h argmax(sim), novelty, eff (lanes 0..3)
    const float gate = gateg[n];
    if (lane < 4) {
        float bs = -1e30f; int as = 0; float mt = -1e30f;
        #pragma unroll
        for (int aa = 0; aa < 4; ++aa) {
            const float sv = sSim[wv][lane * 4 + aa];
            if (sv > bs) { bs = sv; as = aa; }           // first-max (strict >)
            mt = fmaxf(mt, sTsim[wv][lane * 4 + aa]);
        }
        const float novelty = 1.f - mt;
        float e = 0.1f * gate;                            // ETA * gate
        if (!(gate > 0.5f) || !(bs >= 0.f) || !(novelty >= 0.f)) e = 0.f;
        sEff[wv][lane] = e;
        sAst[wv][lane] = as;
    }
    __syncthreads();

    // weighted read of V (all 64 lanes; v = lane, lane+64)
    float r0 = 0.f, r1 = 0.f;
    #pragma unroll
    for (int s2 = 0; s2 < 16; ++s2) {
        const int hh = s2 >> 2, aa = s2 & 3;
        const int rw = (hh * NBUCKET + sIdx[wv][hh]) * ASSOC + aa;
        const float wgt = sW[wv][s2];
        const float* Vp = memV + (size_t)rw * DVAL;
        r0 += wgt * Vp[lane];
        r1 += wgt * Vp[64 + lane];
    }
    readw[(size_t)n * DVAL + lane]      = r0;
    readw[(size_t)n * DVAL + 64 + lane] = r1;

    // gated scatter-add (duplicates accumulate => atomicAdd matches jax .at[].add)
    const float wv0 = wvalg[(size_t)n * DVAL + lane];
    const float wv1 = wvalg[(size_t)n * DVAL + 64 + lane];
    for (int hh = 0; hh < 4; ++hh) {
        const float e = sEff[wv][hh];
        if (e == 0.f) continue;
        const int rw = (hh * NBUCKET + sIdx[wv][hh]) * ASSOC + sAst[wv][hh];
        atomicAdd(&accK[(size_t)rw * DKEY + lane],
                  e * (sWK[wv][lane] - memK[(size_t)rw * DKEY + lane]));
        atomicAdd(&accV[(size_t)rw * DVAL + lane],
                  e * (wv0 - memV[(size_t)rw * DVAL + lane]));
        atomicAdd(&accV[(size_t)rw * DVAL + 64 + lane],
                  e * (wv1 - memV[(size_t)rw * DVAL + 64 + lane]));
        if (lane < 32)
            atomicAdd(&accT[(size_t)rw * DTAG + lane],
                      e * (sWT[wv][lane] - memT[(size_t)rw * DTAG + lane]));
    }
}

// ---------------- launcher ----------------
extern "C" void kernel_launch(void* const* d_in, const int* in_sizes, int n_in,
                              void* d_out, int out_size, void* d_ws, size_t ws_size,
                              hipStream_t stream) {
    const float* u    = (const float*)d_in[0];
    const float* memK = (const float*)d_in[1];
    const float* memV = (const float*)d_in[2];
    const float* memT = (const float*)d_in[3];
    const float* Wq   = (const float*)d_in[4];
    const float* Wwk  = (const float*)d_in[5];
    const float* Wv   = (const float*)d_in[6];
    const float* Wo   = (const float*)d_in[7];
    const float* Wg   = (const float*)d_in[8];
    const float* bg   = (const float*)d_in[9];
    const float* Wvsa = (const float*)d_in[10];
    const float* R    = (const float*)d_in[11];

    const int nK = HN * NBUCKET * ASSOC * DKEY;   // 4,194,304
    const int nV = HN * NBUCKET * ASSOC * DVAL;   // 8,388,608
    const int nT = HN * NBUCKET * ASSOC * DTAG;   // 2,097,152

    float* y_out = (float*)d_out;
    float* K_out = y_out + (size_t)NTOK * DMODEL;
    float* V_out = K_out + nK;
    float* T_out = V_out + nV;

    float* qkeyg = (float*)d_ws;
    float* wkeyg = qkeyg + (size_t)NTOK * DKEY;
    float* wvalg = wkeyg + (size_t)NTOK * DKEY;
    float* gateg = wvalg + (size_t)NTOK * DVAL;
    float* readw = gateg + NTOK;
    // total ws usage: (16384*64*2 + 16384*128*2 + 16384) * 4 B  ~= 24.1 MB

    // 1) outputs double as fp32 scatter accumulators: seed with pristine memories
    hipMemcpyAsync(K_out, memK, (size_t)nK * 4, hipMemcpyDeviceToDevice, stream);
    hipMemcpyAsync(V_out, memV, (size_t)nV * 4, hipMemcpyDeviceToDevice, stream);
    hipMemcpyAsync(T_out, memT, (size_t)nT * 4, hipMemcpyDeviceToDevice, stream);

    // 2) projections
    gemm_tn<<<dim3(NTOK / 64, DKEY / 64), 256, 0, stream>>>(u, Wq,  qkeyg, NTOK, DKEY, DMODEL);
    gemm_tn<<<dim3(NTOK / 64, DKEY / 64), 256, 0, stream>>>(u, Wwk, wkeyg, NTOK, DKEY, DMODEL);
    gemm_tn<<<dim3(NTOK / 64, DVAL / 64), 256, 0, stream>>>(u, Wv,  wvalg, NTOK, DVAL, DMODEL);
    gate_kernel<<<NTOK / 4, 256, 0, stream>>>(u, Wg, bg, gateg);

    // 3) fused routing / gather / score / read / scatter (atomics into d_out)
    route_kernel<<<NTOK / 4, 256, 0, stream>>>(memK, memV, memT, R, Wvsa,
                                               qkeyg, wkeyg, wvalg, gateg,
                                               K_out, V_out, T_out, readw);

    // 4) y = read @ Wo^T
    gemm_tn<<<dim3(NTOK / 64, DMODEL / 64), 256, 0, stream>>>(readw, Wo, y_out, NTOK, DMODEL, DVAL);
}

// Round 3
// 485.341 us; speedup vs baseline: 1.0755x; 1.0755x over previous
//
#include <hip/hip_runtime.h>
#include <hip/hip_bf16.h>
#include <math.h>

#define NTOK    16384
#define DMODEL  1024
#define HN      4
#define NBUCKET 4096
#define ASSOC   4
#define DKEY    64
#define DVAL    128
#define DTAG    32
#define NBITS   12
#define EPSV    1e-6f

typedef __bf16 bf16x8 __attribute__((ext_vector_type(8)));
typedef float  f32x4  __attribute__((ext_vector_type(4)));

__device__ __forceinline__ unsigned short f2bf_raw(float f) {
    __hip_bfloat16 h = __float2bfloat16(f);
    return *(unsigned short*)&h;
}

// ---------------- MFMA GEMM: C[M,N] = A[M,K] @ B[N,K]^T ----------------
// A,B fp32 in global (cast to bf16 during LDS staging), fp32 accumulate/out.
// Tile 128x128, BK=32, 4 waves (2x2 of 64x64), 16x16x32 bf16 MFMA.
__global__ __launch_bounds__(256) void gemm_mfma(const float* __restrict__ A,
                                                 const float* __restrict__ B,
                                                 float* __restrict__ C,
                                                 int M, int N, int K) {
    // LDS: [kgroup 0..3][row 0..127][8 elems] ; fragment reads are 16B, 2-way banked (free)
    __shared__ __align__(16) unsigned short As[4][128][8];
    __shared__ __align__(16) unsigned short Bs[4][128][8];
    const int t    = threadIdx.x;
    const int lane = t & 63;
    const int w    = t >> 6;
    const int wm   = (w & 1) * 64;
    const int wn   = (w >> 1) * 64;
    const int bm   = blockIdx.x * 128;
    const int bn   = blockIdx.y * 128;

    const int srow = t & 127;       // staging row
    const int skg  = t >> 7;        // staging kgroup base (0 or 1; +2 on second issue)
    const float* Ap = A + (size_t)(bm + srow) * K;
    const float* Bp = B + (size_t)(bn + srow) * K;

    const int fr = lane & 15;       // fragment row/col
    const int kq = lane >> 4;       // k-quad

    f32x4 acc[4][4] = {};

    for (int k0 = 0; k0 < K; k0 += 32) {
        #pragma unroll
        for (int ii = 0; ii < 2; ++ii) {
            const int kg = skg + ii * 2;
            const float4 a0 = *(const float4*)(Ap + k0 + kg * 8);
            const float4 a1 = *(const float4*)(Ap + k0 + kg * 8 + 4);
            const float4 b0 = *(const float4*)(Bp + k0 + kg * 8);
            const float4 b1 = *(const float4*)(Bp + k0 + kg * 8 + 4);
            unsigned short* da = &As[kg][srow][0];
            da[0] = f2bf_raw(a0.x); da[1] = f2bf_raw(a0.y);
            da[2] = f2bf_raw(a0.z); da[3] = f2bf_raw(a0.w);
            da[4] = f2bf_raw(a1.x); da[5] = f2bf_raw(a1.y);
            da[6] = f2bf_raw(a1.z); da[7] = f2bf_raw(a1.w);
            unsigned short* db = &Bs[kg][srow][0];
            db[0] = f2bf_raw(b0.x); db[1] = f2bf_raw(b0.y);
            db[2] = f2bf_raw(b0.z); db[3] = f2bf_raw(b0.w);
            db[4] = f2bf_raw(b1.x); db[5] = f2bf_raw(b1.y);
            db[6] = f2bf_raw(b1.z); db[7] = f2bf_raw(b1.w);
        }
        __syncthreads();
        bf16x8 af[4], bfv[4];
        #pragma unroll
        for (int i = 0; i < 4; ++i) af[i]  = *(const bf16x8*)&As[kq][wm + i * 16 + fr][0];
        #pragma unroll
        for (int j = 0; j < 4; ++j) bfv[j] = *(const bf16x8*)&Bs[kq][wn + j * 16 + fr][0];
        #pragma unroll
        for (int i = 0; i < 4; ++i)
            #pragma unroll
            for (int j = 0; j < 4; ++j)
                acc[i][j] = __builtin_amdgcn_mfma_f32_16x16x32_bf16(af[i], bfv[j], acc[i][j], 0, 0, 0);
        __syncthreads();
    }
    // C/D layout (m89-verified): col = lane&15, row = (lane>>4)*4 + reg
    #pragma unroll
    for (int i = 0; i < 4; ++i)
        #pragma unroll
        for (int j = 0; j < 4; ++j)
            #pragma unroll
            for (int r = 0; r < 4; ++r)
                C[(size_t)(bm + wm + i * 16 + kq * 4 + r) * N + (bn + wn + j * 16 + fr)] = acc[i][j][r];
}

// ---------------- fp32 GEMM (routing-critical): C[M,128] = A[M,K] @ B[128,K]^T ----
// tile 64x128, BK=16, micro-tile 4x8 per thread
__global__ __launch_bounds__(256) void gemm_f32(const float* __restrict__ A,
                                                const float* __restrict__ B,
                                                float* __restrict__ C,
                                                int M, int N, int K) {
    __shared__ __align__(16) float As[16][68];
    __shared__ __align__(16) float Bs[16][136];
    const int t  = threadIdx.x;
    const int bm = blockIdx.x * 64;
    const int bn = blockIdx.y * 128;
    const int tx = t & 15;
    const int ty = t >> 4;
    float acc[4][8] = {};
    const int arow = t >> 2, ac = (t & 3) * 4;
    const int brow = t >> 1, bc = (t & 1) * 8;
    for (int k0 = 0; k0 < K; k0 += 16) {
        const float4 av = *(const float4*)(A + (size_t)(bm + arow) * K + k0 + ac);
        const float4 b0 = *(const float4*)(B + (size_t)(bn + brow) * K + k0 + bc);
        const float4 b1 = *(const float4*)(B + (size_t)(bn + brow) * K + k0 + bc + 4);
        As[ac + 0][arow] = av.x; As[ac + 1][arow] = av.y;
        As[ac + 2][arow] = av.z; As[ac + 3][arow] = av.w;
        Bs[bc + 0][brow] = b0.x; Bs[bc + 1][brow] = b0.y;
        Bs[bc + 2][brow] = b0.z; Bs[bc + 3][brow] = b0.w;
        Bs[bc + 4][brow] = b1.x; Bs[bc + 5][brow] = b1.y;
        Bs[bc + 6][brow] = b1.z; Bs[bc + 7][brow] = b1.w;
        __syncthreads();
        #pragma unroll
        for (int kk = 0; kk < 16; ++kk) {
            const float4 a4 = *(const float4*)&As[kk][ty * 4];
            const float4 bb0 = *(const float4*)&Bs[kk][tx * 8];
            const float4 bb1 = *(const float4*)&Bs[kk][tx * 8 + 4];
            const float a[4] = {a4.x, a4.y, a4.z, a4.w};
            const float b[8] = {bb0.x, bb0.y, bb0.z, bb0.w, bb1.x, bb1.y, bb1.z, bb1.w};
            #pragma unroll
            for (int i = 0; i < 4; ++i)
                #pragma unroll
                for (int j = 0; j < 8; ++j)
                    acc[i][j] = fmaf(a[i], b[j], acc[i][j]);
        }
        __syncthreads();
    }
    #pragma unroll
    for (int i = 0; i < 4; ++i)
        #pragma unroll
        for (int j = 0; j < 8; ++j)
            C[(size_t)(bm + ty * 4 + i) * N + bn + tx * 8 + j] = acc[i][j];
}

// ---------------- gate = sigmoid(u . Wg + bg) ----------------
__global__ __launch_bounds__(256) void gate_kernel(const float* __restrict__ u,
                                                   const float* __restrict__ Wg,
                                                   const float* __restrict__ bg,
                                                   float* __restrict__ gateg) {
    const int wv = threadIdx.x >> 6, lane = threadIdx.x & 63;
    const int n = blockIdx.x * 4 + wv;
    const float* up = u + (size_t)n * DMODEL;
    float acc = 0.f;
    #pragma unroll
    for (int j = 0; j < 16; ++j)
        acc += up[lane + 64 * j] * Wg[lane + 64 * j];
    #pragma unroll
    for (int off = 1; off < 64; off <<= 1) acc += __shfl_xor(acc, off);
    if (lane == 0) gateg[n] = 1.f / (1.f + expf(-(acc + bg[0])));
}

// ---------------- fused routing / gather / score / read / scatter ----------------
// one wave per token; qw holds [qkey(64) | wkey(64)] per token
__global__ __launch_bounds__(256) void route_kernel(
    const float* __restrict__ memK, const float* __restrict__ memV,
    const float* __restrict__ memT, const float* __restrict__ R,
    const float* __restrict__ Wvsa,
    const float* __restrict__ qw, const float* __restrict__ wvalg,
    const float* __restrict__ gateg,
    float* __restrict__ accK, float* __restrict__ accV, float* __restrict__ accT,
    float* __restrict__ readw) {
    __shared__ float sQK[4][64], sWK[4][64], sQT[4][32], sWT[4][32];
    __shared__ float sSc[4][16], sSim[4][16], sTsim[4][16], sW[4][16];
    __shared__ int   sIdx[4][4], sAst[4][4];
    __shared__ float sEff[4][4];

    const int wv = threadIdx.x >> 6;
    const int lane = threadIdx.x & 63;
    const int n = blockIdx.x * 4 + wv;

    const float qk = qw[(size_t)n * 128 + lane];
    const float wk = qw[(size_t)n * 128 + 64 + lane];
    sQK[wv][lane] = qk;
    sWK[wv][lane] = wk;
    float wk2 = wk * wk;
    #pragma unroll
    for (int off = 1; off < 64; off <<= 1) wk2 += __shfl_xor(wk2, off);
    const float wknorm = sqrtf(wk2) + EPSV;
    __syncthreads();

    {
        const int tg = lane & 31;
        const float* keyp = (lane < 32) ? sQK[wv] : sWK[wv];
        float tacc = 0.f;
        for (int d = 0; d < 64; ++d) tacc += keyp[d] * Wvsa[d * DTAG + tg];
        const float tagv = tanhf(tacc);
        if (lane < 32) sQT[wv][tg] = tagv; else sWT[wv][tg] = tagv;
        float wt2 = (lane >= 32) ? tagv * tagv : 0.f;
        #pragma unroll
        for (int off = 1; off < 64; off <<= 1) wt2 += __shfl_xor(wt2, off);
        const float wtnorm = sqrtf(wt2) + EPSV;

        bool bit = false;
        if (lane < 48) {
            const int h = lane / 12, k = lane % 12;
            float bacc = 0.f;
            for (int d = 0; d < 64; ++d)
                bacc += sQK[wv][d] * R[(size_t)(h * DKEY + d) * NBITS + k];
            bit = bacc > 0.f;
        }
        const unsigned long long mask = __ballot(bit);
        if (lane < 4) sIdx[wv][lane] = (int)((mask >> (12 * lane)) & 0xFFFull);
        __syncthreads();

        const int slot = lane >> 2, sub = lane & 3;
        const int sh = slot >> 2, sa = slot & 3;
        const int rowS = (sh * NBUCKET + sIdx[wv][sh]) * ASSOC + sa;
        const float* Kp = memK + (size_t)rowS * DKEY;
        const float* Tp = memT + (size_t)rowS * DTAG;
        float d_qk = 0, d_wk = 0, d_kk = 0, d_qt = 0, d_wt = 0, d_tt = 0;
        for (int j = 0; j < 16; ++j) {
            const int d = sub * 16 + j;
            const float kv = Kp[d];
            d_qk += sQK[wv][d] * kv;
            d_wk += sWK[wv][d] * kv;
            d_kk += kv * kv;
        }
        for (int j = 0; j < 8; ++j) {
            const int d = sub * 8 + j;
            const float tv = Tp[d];
            d_qt += sQT[wv][d] * tv;
            d_wt += sWT[wv][d] * tv;
            d_tt += tv * tv;
        }
        #pragma unroll
        for (int off = 1; off <= 2; off <<= 1) {
            d_qk += __shfl_xor(d_qk, off);
            d_wk += __shfl_xor(d_wk, off);
            d_kk += __shfl_xor(d_kk, off);
            d_qt += __shfl_xor(d_qt, off);
            d_wt += __shfl_xor(d_wt, off);
            d_tt += __shfl_xor(d_tt, off);
        }
        if (sub == 0) {
            sSc[wv][slot]   = d_qk * 0.125f + d_qt * 0.17677669529663687f;
            sSim[wv][slot]  = d_wk / (wknorm * (sqrtf(d_kk) + EPSV));
            sTsim[wv][slot] = d_wt / (wtnorm * (sqrtf(d_tt) + EPSV));
        }
    }
    __syncthreads();

    if (lane < 16) {
        const float sc = sSc[wv][lane];
        float m = sc;
        #pragma unroll
        for (int off = 1; off < 16; off <<= 1) m = fmaxf(m, __shfl_xor(m, off, 16));
        const float e = expf(sc - m);
        float ssum = e;
        #pragma unroll
        for (int off = 1; off < 16; off <<= 1) ssum += __shfl_xor(ssum, off, 16);
        sW[wv][lane] = e / ssum;
    }
    const float gate = gateg[n];
    if (lane < 4) {
        float bs = -1e30f; int as = 0; float mt = -1e30f;
        #pragma unroll
        for (int aa = 0; aa < 4; ++aa) {
            const float sv = sSim[wv][lane * 4 + aa];
            if (sv > bs) { bs = sv; as = aa; }
            mt = fmaxf(mt, sTsim[wv][lane * 4 + aa]);
        }
        const float novelty = 1.f - mt;
        float e = 0.1f * gate;
        if (!(gate > 0.5f) || !(bs >= 0.f) || !(novelty >= 0.f)) e = 0.f;
        sEff[wv][lane] = e;
        sAst[wv][lane] = as;
    }
    __syncthreads();

    float r0 = 0.f, r1 = 0.f;
    #pragma unroll
    for (int s2 = 0; s2 < 16; ++s2) {
        const int hh = s2 >> 2, aa = s2 & 3;
        const int rw = (hh * NBUCKET + sIdx[wv][hh]) * ASSOC + aa;
        const float wgt = sW[wv][s2];
        const float* Vp = memV + (size_t)rw * DVAL;
        r0 += wgt * Vp[lane];
        r1 += wgt * Vp[64 + lane];
    }
    readw[(size_t)n * DVAL + lane]      = r0;
    readw[(size_t)n * DVAL + 64 + lane] = r1;

    const float wv0 = wvalg[(size_t)n * DVAL + lane];
    const float wv1 = wvalg[(size_t)n * DVAL + 64 + lane];
    for (int hh = 0; hh < 4; ++hh) {
        const float e = sEff[wv][hh];
        if (e == 0.f) continue;
        const int rw = (hh * NBUCKET + sIdx[wv][hh]) * ASSOC + sAst[wv][hh];
        atomicAdd(&accK[(size_t)rw * DKEY + lane],
                  e * (sWK[wv][lane] - memK[(size_t)rw * DKEY + lane]));
        atomicAdd(&accV[(size_t)rw * DVAL + lane],
                  e * (wv0 - memV[(size_t)rw * DVAL + lane]));
        atomicAdd(&accV[(size_t)rw * DVAL + 64 + lane],
                  e * (wv1 - memV[(size_t)rw * DVAL + 64 + lane]));
        if (lane < 32)
            atomicAdd(&accT[(size_t)rw * DTAG + lane],
                      e * (sWT[wv][lane] - memT[(size_t)rw * DTAG + lane]));
    }
}

// ---------------- launcher ----------------
extern "C" void kernel_launch(void* const* d_in, const int* in_sizes, int n_in,
                              void* d_out, int out_size, void* d_ws, size_t ws_size,
                              hipStream_t stream) {
    const float* u    = (const float*)d_in[0];
    const float* memK = (const float*)d_in[1];
    const float* memV = (const float*)d_in[2];
    const float* memT = (const float*)d_in[3];
    const float* Wq   = (const float*)d_in[4];
    const float* Wwk  = (const float*)d_in[5];
    const float* Wv   = (const float*)d_in[6];
    const float* Wo   = (const float*)d_in[7];
    const float* Wg   = (const float*)d_in[8];
    const float* bg   = (const float*)d_in[9];
    const float* Wvsa = (const float*)d_in[10];
    const float* R    = (const float*)d_in[11];

    const int nK = HN * NBUCKET * ASSOC * DKEY;   // 4,194,304
    const int nV = HN * NBUCKET * ASSOC * DVAL;   // 8,388,608
    const int nT = HN * NBUCKET * ASSOC * DTAG;   // 2,097,152

    float* y_out = (float*)d_out;
    float* K_out = y_out + (size_t)NTOK * DMODEL;
    float* V_out = K_out + nK;
    float* T_out = V_out + nV;

    float* qw    = (float*)d_ws;                       // [NTOK][128] qkey|wkey
    float* wvalg = qw    + (size_t)NTOK * 128;         // [NTOK][128]
    float* readw = wvalg + (size_t)NTOK * 128;         // [NTOK][128]
    float* gateg = readw + (size_t)NTOK * 128;         // [NTOK]
    float* qwW   = gateg + NTOK;                       // [128][1024] cat(Wq,Wwk)
    // ws usage ~ 25.8 MB

    // 0) concat routing weights; seed outputs with pristine memories
    hipMemcpyAsync(qwW,          Wq,  (size_t)DKEY * DMODEL * 4, hipMemcpyDeviceToDevice, stream);
    hipMemcpyAsync(qwW + 65536,  Wwk, (size_t)DKEY * DMODEL * 4, hipMemcpyDeviceToDevice, stream);
    hipMemcpyAsync(K_out, memK, (size_t)nK * 4, hipMemcpyDeviceToDevice, stream);
    hipMemcpyAsync(V_out, memV, (size_t)nV * 4, hipMemcpyDeviceToDevice, stream);
    hipMemcpyAsync(T_out, memT, (size_t)nT * 4, hipMemcpyDeviceToDevice, stream);

    // 1) projections: routing-critical in fp32, value in bf16 MFMA
    gemm_f32 <<<dim3(NTOK / 64, 1),   256, 0, stream>>>(u, qwW, qw,    NTOK, 128,  DMODEL);
    gemm_mfma<<<dim3(NTOK / 128, 1),  256, 0, stream>>>(u, Wv,  wvalg, NTOK, DVAL, DMODEL);
    gate_kernel<<<NTOK / 4, 256, 0, stream>>>(u, Wg, bg, gateg);

    // 2) fused routing / gather / score / read / scatter (atomics into d_out)
    route_kernel<<<NTOK / 4, 256, 0, stream>>>(memK, memV, memT, R, Wvsa,
                                               qw, wvalg, gateg,
                                               K_out, V_out, T_out, readw);

    // 3) y = read @ Wo^T (bf16 MFMA)
    gemm_mfma<<<dim3(NTOK / 128, DMODEL / 128), 256, 0, stream>>>(readw, Wo, y_out, NTOK, DMODEL, DVAL);
}

// Round 4
// 438.943 us; speedup vs baseline: 1.1892x; 1.1057x over previous
//
#include <hip/hip_runtime.h>
#include <hip/hip_bf16.h>
#include <math.h>

#define NTOK    16384
#define DMODEL  1024
#define HN      4
#define NBUCKET 4096
#define ASSOC   4
#define DKEY    64
#define DVAL    128
#define DTAG    32
#define NBITS   12
#define EPSV    1e-6f

typedef __bf16 bf16x8 __attribute__((ext_vector_type(8)));
typedef float  f32x4  __attribute__((ext_vector_type(4)));

__device__ __forceinline__ unsigned short f2bf_raw(float f) {
    __hip_bfloat16 h = __float2bfloat16(f);
    return *(unsigned short*)&h;
}

// ---------------- MFMA GEMM 128x128 tile: C[M,N] = A[M,K] @ B[N,K]^T ----------------
__global__ __launch_bounds__(256) void gemm_mfma(const float* __restrict__ A,
                                                 const float* __restrict__ B,
                                                 float* __restrict__ C,
                                                 int M, int N, int K) {
    __shared__ __align__(16) unsigned short As[4][128][8];
    __shared__ __align__(16) unsigned short Bs[4][128][8];
    const int t    = threadIdx.x;
    const int lane = t & 63;
    const int w    = t >> 6;
    const int wm   = (w & 1) * 64;
    const int wn   = (w >> 1) * 64;
    const int bm   = blockIdx.x * 128;
    const int bn   = blockIdx.y * 128;

    const int srow = t & 127;
    const int skg  = t >> 7;
    const float* Ap = A + (size_t)(bm + srow) * K;
    const float* Bp = B + (size_t)(bn + srow) * K;

    const int fr = lane & 15;
    const int kq = lane >> 4;

    f32x4 acc[4][4] = {};

    for (int k0 = 0; k0 < K; k0 += 32) {
        #pragma unroll
        for (int ii = 0; ii < 2; ++ii) {
            const int kg = skg + ii * 2;
            const float4 a0 = *(const float4*)(Ap + k0 + kg * 8);
            const float4 a1 = *(const float4*)(Ap + k0 + kg * 8 + 4);
            const float4 b0 = *(const float4*)(Bp + k0 + kg * 8);
            const float4 b1 = *(const float4*)(Bp + k0 + kg * 8 + 4);
            unsigned short* da = &As[kg][srow][0];
            da[0] = f2bf_raw(a0.x); da[1] = f2bf_raw(a0.y);
            da[2] = f2bf_raw(a0.z); da[3] = f2bf_raw(a0.w);
            da[4] = f2bf_raw(a1.x); da[5] = f2bf_raw(a1.y);
            da[6] = f2bf_raw(a1.z); da[7] = f2bf_raw(a1.w);
            unsigned short* db = &Bs[kg][srow][0];
            db[0] = f2bf_raw(b0.x); db[1] = f2bf_raw(b0.y);
            db[2] = f2bf_raw(b0.z); db[3] = f2bf_raw(b0.w);
            db[4] = f2bf_raw(b1.x); db[5] = f2bf_raw(b1.y);
            db[6] = f2bf_raw(b1.z); db[7] = f2bf_raw(b1.w);
        }
        __syncthreads();
        bf16x8 af[4], bfv[4];
        #pragma unroll
        for (int i = 0; i < 4; ++i) af[i]  = *(const bf16x8*)&As[kq][wm + i * 16 + fr][0];
        #pragma unroll
        for (int j = 0; j < 4; ++j) bfv[j] = *(const bf16x8*)&Bs[kq][wn + j * 16 + fr][0];
        #pragma unroll
        for (int i = 0; i < 4; ++i)
            #pragma unroll
            for (int j = 0; j < 4; ++j)
                acc[i][j] = __builtin_amdgcn_mfma_f32_16x16x32_bf16(af[i], bfv[j], acc[i][j], 0, 0, 0);
        __syncthreads();
    }
    #pragma unroll
    for (int i = 0; i < 4; ++i)
        #pragma unroll
        for (int j = 0; j < 4; ++j)
            #pragma unroll
            for (int r = 0; r < 4; ++r)
                C[(size_t)(bm + wm + i * 16 + kq * 4 + r) * N + (bn + wn + j * 16 + fr)] = acc[i][j][r];
}

// ---------------- MFMA GEMM 128x64 tile (for skinny N): 4 waves stacked on M ----------
__global__ __launch_bounds__(256) void gemm_mfma_n64(const float* __restrict__ A,
                                                     const float* __restrict__ B,
                                                     float* __restrict__ C,
                                                     int M, int N, int K) {
    __shared__ __align__(16) unsigned short As[4][128][8];
    __shared__ __align__(16) unsigned short Bs[4][64][8];
    const int t    = threadIdx.x;
    const int lane = t & 63;
    const int w    = t >> 6;           // wave: rows w*32 .. w*32+31
    const int bm   = blockIdx.x * 128;
    const int bn   = blockIdx.y * 64;

    const int srow = t & 127;
    const int skg  = t >> 7;
    const float* Ap = A + (size_t)(bm + srow) * K;
    const float* Bp = B + (size_t)(bn + (t & 63)) * K;
    const int bkg   = t >> 6;

    const int fr = lane & 15;
    const int kq = lane >> 4;

    f32x4 acc[2][4] = {};

    for (int k0 = 0; k0 < K; k0 += 32) {
        #pragma unroll
        for (int ii = 0; ii < 2; ++ii) {
            const int kg = skg + ii * 2;
            const float4 a0 = *(const float4*)(Ap + k0 + kg * 8);
            const float4 a1 = *(const float4*)(Ap + k0 + kg * 8 + 4);
            unsigned short* da = &As[kg][srow][0];
            da[0] = f2bf_raw(a0.x); da[1] = f2bf_raw(a0.y);
            da[2] = f2bf_raw(a0.z); da[3] = f2bf_raw(a0.w);
            da[4] = f2bf_raw(a1.x); da[5] = f2bf_raw(a1.y);
            da[6] = f2bf_raw(a1.z); da[7] = f2bf_raw(a1.w);
        }
        {
            const float4 b0 = *(const float4*)(Bp + k0 + bkg * 8);
            const float4 b1 = *(const float4*)(Bp + k0 + bkg * 8 + 4);
            unsigned short* db = &Bs[bkg][t & 63][0];
            db[0] = f2bf_raw(b0.x); db[1] = f2bf_raw(b0.y);
            db[2] = f2bf_raw(b0.z); db[3] = f2bf_raw(b0.w);
            db[4] = f2bf_raw(b1.x); db[5] = f2bf_raw(b1.y);
            db[6] = f2bf_raw(b1.z); db[7] = f2bf_raw(b1.w);
        }
        __syncthreads();
        bf16x8 af[2], bfv[4];
        #pragma unroll
        for (int i = 0; i < 2; ++i) af[i]  = *(const bf16x8*)&As[kq][w * 32 + i * 16 + fr][0];
        #pragma unroll
        for (int j = 0; j < 4; ++j) bfv[j] = *(const bf16x8*)&Bs[kq][j * 16 + fr][0];
        #pragma unroll
        for (int i = 0; i < 2; ++i)
            #pragma unroll
            for (int j = 0; j < 4; ++j)
                acc[i][j] = __builtin_amdgcn_mfma_f32_16x16x32_bf16(af[i], bfv[j], acc[i][j], 0, 0, 0);
        __syncthreads();
    }
    #pragma unroll
    for (int i = 0; i < 2; ++i)
        #pragma unroll
        for (int j = 0; j < 4; ++j)
            #pragma unroll
            for (int r = 0; r < 4; ++r)
                C[(size_t)(bm + w * 32 + i * 16 + kq * 4 + r) * N + (bn + j * 16 + fr)] = acc[i][j][r];
}

// ---------------- fp32 GEMM split-K: Cpart[z][M,128] = A[M, z-half] @ B[:, z-half]^T ----
__global__ __launch_bounds__(256) void gemm_f32_splitk(const float* __restrict__ A,
                                                       const float* __restrict__ B,
                                                       float* __restrict__ Cpart,
                                                       int M, int K, int K_half) {
    __shared__ __align__(16) float As[16][68];
    __shared__ __align__(16) float Bs[16][136];
    const int t  = threadIdx.x;
    const int bm = blockIdx.x * 64;
    const int kz = blockIdx.z;
    const int tx = t & 15;
    const int ty = t >> 4;
    float acc[4][8] = {};
    const int arow = t >> 2, ac = (t & 3) * 4;
    const int brow = t >> 1, bc = (t & 1) * 8;
    const int kbeg = kz * K_half, kend = kbeg + K_half;
    for (int k0 = kbeg; k0 < kend; k0 += 16) {
        const float4 av = *(const float4*)(A + (size_t)(bm + arow) * K + k0 + ac);
        const float4 b0 = *(const float4*)(B + (size_t)brow * K + k0 + bc);
        const float4 b1 = *(const float4*)(B + (size_t)brow * K + k0 + bc + 4);
        As[ac + 0][arow] = av.x; As[ac + 1][arow] = av.y;
        As[ac + 2][arow] = av.z; As[ac + 3][arow] = av.w;
        Bs[bc + 0][brow] = b0.x; Bs[bc + 1][brow] = b0.y;
        Bs[bc + 2][brow] = b0.z; Bs[bc + 3][brow] = b0.w;
        Bs[bc + 4][brow] = b1.x; Bs[bc + 5][brow] = b1.y;
        Bs[bc + 6][brow] = b1.z; Bs[bc + 7][brow] = b1.w;
        __syncthreads();
        #pragma unroll
        for (int kk = 0; kk < 16; ++kk) {
            const float4 a4  = *(const float4*)&As[kk][ty * 4];
            const float4 bb0 = *(const float4*)&Bs[kk][tx * 8];
            const float4 bb1 = *(const float4*)&Bs[kk][tx * 8 + 4];
            const float a[4] = {a4.x, a4.y, a4.z, a4.w};
            const float b[8] = {bb0.x, bb0.y, bb0.z, bb0.w, bb1.x, bb1.y, bb1.z, bb1.w};
            #pragma unroll
            for (int i = 0; i < 4; ++i)
                #pragma unroll
                for (int j = 0; j < 8; ++j)
                    acc[i][j] = fmaf(a[i], b[j], acc[i][j]);
        }
        __syncthreads();
    }
    float* Cp = Cpart + (size_t)kz * M * 128;
    #pragma unroll
    for (int i = 0; i < 4; ++i)
        #pragma unroll
        for (int j = 0; j < 8; ++j)
            Cp[(size_t)(bm + ty * 4 + i) * 128 + tx * 8 + j] = acc[i][j];
}

// ---------------- deterministic split-K reduce: out = p0 + p1 ----------------
__global__ __launch_bounds__(256) void reduce2_kernel(const float* __restrict__ p0,
                                                      const float* __restrict__ p1,
                                                      float* __restrict__ out, int n4) {
    const int i = (blockIdx.x * 256 + threadIdx.x);
    if (i < n4) {
        const float4 a = ((const float4*)p0)[i];
        const float4 b = ((const float4*)p1)[i];
        float4 r; r.x = a.x + b.x; r.y = a.y + b.y; r.z = a.z + b.z; r.w = a.w + b.w;
        ((float4*)out)[i] = r;
    }
}

// ---------------- gate = sigmoid(u . Wg + bg) ----------------
__global__ __launch_bounds__(256) void gate_kernel(const float* __restrict__ u,
                                                   const float* __restrict__ Wg,
                                                   const float* __restrict__ bg,
                                                   float* __restrict__ gateg) {
    const int wv = threadIdx.x >> 6, lane = threadIdx.x & 63;
    const int n = blockIdx.x * 4 + wv;
    const float* up = u + (size_t)n * DMODEL;
    float acc = 0.f;
    #pragma unroll
    for (int j = 0; j < 16; ++j)
        acc += up[lane + 64 * j] * Wg[lane + 64 * j];
    #pragma unroll
    for (int off = 1; off < 64; off <<= 1) acc += __shfl_xor(acc, off);
    if (lane == 0) gateg[n] = 1.f / (1.f + expf(-(acc + bg[0])));
}

// ---------------- fused routing / gather / score / read / scatter ----------------
__global__ __launch_bounds__(256) void route_kernel(
    const float* __restrict__ memK, const float* __restrict__ memV,
    const float* __restrict__ memT, const float* __restrict__ R,
    const float* __restrict__ Wvsa,
    const float* __restrict__ qw, const float* __restrict__ wvalg,
    const float* __restrict__ gateg,
    float* __restrict__ accK, float* __restrict__ accV, float* __restrict__ accT,
    float* __restrict__ readw) {
    __shared__ float sQK[4][64], sWK[4][64], sQT[4][32], sWT[4][32];
    __shared__ float sSc[4][16], sSim[4][16], sTsim[4][16], sW[4][16];
    __shared__ int   sIdx[4][4], sAst[4][4];
    __shared__ float sEff[4][4];

    const int wv = threadIdx.x >> 6;
    const int lane = threadIdx.x & 63;
    const int n = blockIdx.x * 4 + wv;

    const float qk = qw[(size_t)n * 128 + lane];
    const float wk = qw[(size_t)n * 128 + 64 + lane];
    sQK[wv][lane] = qk;
    sWK[wv][lane] = wk;
    float wk2 = wk * wk;
    #pragma unroll
    for (int off = 1; off < 64; off <<= 1) wk2 += __shfl_xor(wk2, off);
    const float wknorm = sqrtf(wk2) + EPSV;
    __syncthreads();

    {
        const int tg = lane & 31;
        const float* keyp = (lane < 32) ? sQK[wv] : sWK[wv];
        float tacc = 0.f;
        for (int d = 0; d < 64; ++d) tacc += keyp[d] * Wvsa[d * DTAG + tg];
        const float tagv = tanhf(tacc);
        if (lane < 32) sQT[wv][tg] = tagv; else sWT[wv][tg] = tagv;
        float wt2 = (lane >= 32) ? tagv * tagv : 0.f;
        #pragma unroll
        for (int off = 1; off < 64; off <<= 1) wt2 += __shfl_xor(wt2, off);
        const float wtnorm = sqrtf(wt2) + EPSV;

        bool bit = false;
        if (lane < 48) {
            const int h = lane / 12, k = lane % 12;
            float bacc = 0.f;
            for (int d = 0; d < 64; ++d)
                bacc += sQK[wv][d] * R[(size_t)(h * DKEY + d) * NBITS + k];
            bit = bacc > 0.f;
        }
        const unsigned long long mask = __ballot(bit);
        if (lane < 4) sIdx[wv][lane] = (int)((mask >> (12 * lane)) & 0xFFFull);
        __syncthreads();

        const int slot = lane >> 2, sub = lane & 3;
        const int sh = slot >> 2, sa = slot & 3;
        const int rowS = (sh * NBUCKET + sIdx[wv][sh]) * ASSOC + sa;
        const float* Kp = memK + (size_t)rowS * DKEY;
        const float* Tp = memT + (size_t)rowS * DTAG;
        float d_qk = 0, d_wk = 0, d_kk = 0, d_qt = 0, d_wt = 0, d_tt = 0;
        for (int j = 0; j < 16; ++j) {
            const int d = sub * 16 + j;
            const float kv = Kp[d];
            d_qk += sQK[wv][d] * kv;
            d_wk += sWK[wv][d] * kv;
            d_kk += kv * kv;
        }
        for (int j = 0; j < 8; ++j) {
            const int d = sub * 8 + j;
            const float tv = Tp[d];
            d_qt += sQT[wv][d] * tv;
            d_wt += sWT[wv][d] * tv;
            d_tt += tv * tv;
        }
        #pragma unroll
        for (int off = 1; off <= 2; off <<= 1) {
            d_qk += __shfl_xor(d_qk, off);
            d_wk += __shfl_xor(d_wk, off);
            d_kk += __shfl_xor(d_kk, off);
            d_qt += __shfl_xor(d_qt, off);
            d_wt += __shfl_xor(d_wt, off);
            d_tt += __shfl_xor(d_tt, off);
        }
        if (sub == 0) {
            sSc[wv][slot]   = d_qk * 0.125f + d_qt * 0.17677669529663687f;
            sSim[wv][slot]  = d_wk / (wknorm * (sqrtf(d_kk) + EPSV));
            sTsim[wv][slot] = d_wt / (wtnorm * (sqrtf(d_tt) + EPSV));
        }
    }
    __syncthreads();

    if (lane < 16) {
        const float sc = sSc[wv][lane];
        float m = sc;
        #pragma unroll
        for (int off = 1; off < 16; off <<= 1) m = fmaxf(m, __shfl_xor(m, off, 16));
        const float e = expf(sc - m);
        float ssum = e;
        #pragma unroll
        for (int off = 1; off < 16; off <<= 1) ssum += __shfl_xor(ssum, off, 16);
        sW[wv][lane] = e / ssum;
    }
    const float gate = gateg[n];
    if (lane < 4) {
        float bs = -1e30f; int as = 0; float mt = -1e30f;
        #pragma unroll
        for (int aa = 0; aa < 4; ++aa) {
            const float sv = sSim[wv][lane * 4 + aa];
            if (sv > bs) { bs = sv; as = aa; }
            mt = fmaxf(mt, sTsim[wv][lane * 4 + aa]);
        }
        const float novelty = 1.f - mt;
        float e = 0.1f * gate;
        if (!(gate > 0.5f) || !(bs >= 0.f) || !(novelty >= 0.f)) e = 0.f;
        sEff[wv][lane] = e;
        sAst[wv][lane] = as;
    }
    __syncthreads();

    float r0 = 0.f, r1 = 0.f;
    #pragma unroll
    for (int s2 = 0; s2 < 16; ++s2) {
        const int hh = s2 >> 2, aa = s2 & 3;
        const int rw = (hh * NBUCKET + sIdx[wv][hh]) * ASSOC + aa;
        const float wgt = sW[wv][s2];
        const float* Vp = memV + (size_t)rw * DVAL;
        r0 += wgt * Vp[lane];
        r1 += wgt * Vp[64 + lane];
    }
    readw[(size_t)n * DVAL + lane]      = r0;
    readw[(size_t)n * DVAL + 64 + lane] = r1;

    const float wv0 = wvalg[(size_t)n * DVAL + lane];
    const float wv1 = wvalg[(size_t)n * DVAL + 64 + lane];
    for (int hh = 0; hh < 4; ++hh) {
        const float e = sEff[wv][hh];
        if (e == 0.f) continue;
        const int rw = (hh * NBUCKET + sIdx[wv][hh]) * ASSOC + sAst[wv][hh];
        atomicAdd(&accK[(size_t)rw * DKEY + lane],
                  e * (sWK[wv][lane] - memK[(size_t)rw * DKEY + lane]));
        atomicAdd(&accV[(size_t)rw * DVAL + lane],
                  e * (wv0 - memV[(size_t)rw * DVAL + lane]));
        atomicAdd(&accV[(size_t)rw * DVAL + 64 + lane],
                  e * (wv1 - memV[(size_t)rw * DVAL + 64 + lane]));
        if (lane < 32)
            atomicAdd(&accT[(size_t)rw * DTAG + lane],
                      e * (sWT[wv][lane] - memT[(size_t)rw * DTAG + lane]));
    }
}

// ---------------- launcher ----------------
extern "C" void kernel_launch(void* const* d_in, const int* in_sizes, int n_in,
                              void* d_out, int out_size, void* d_ws, size_t ws_size,
                              hipStream_t stream) {
    const float* u    = (const float*)d_in[0];
    const float* memK = (const float*)d_in[1];
    const float* memV = (const float*)d_in[2];
    const float* memT = (const float*)d_in[3];
    const float* Wq   = (const float*)d_in[4];
    const float* Wwk  = (const float*)d_in[5];
    const float* Wv   = (const float*)d_in[6];
    const float* Wo   = (const float*)d_in[7];
    const float* Wg   = (const float*)d_in[8];
    const float* bg   = (const float*)d_in[9];
    const float* Wvsa = (const float*)d_in[10];
    const float* R    = (const float*)d_in[11];

    const int nK = HN * NBUCKET * ASSOC * DKEY;   // 4,194,304
    const int nV = HN * NBUCKET * ASSOC * DVAL;   // 8,388,608
    const int nT = HN * NBUCKET * ASSOC * DTAG;   // 2,097,152

    float* y_out = (float*)d_out;
    float* K_out = y_out + (size_t)NTOK * DMODEL;
    float* V_out = K_out + nK;
    float* T_out = V_out + nV;

    float* qw    = (float*)d_ws;                       // [NTOK][128] qkey|wkey
    float* wvalg = qw    + (size_t)NTOK * 128;         // [NTOK][128]
    float* readw = wvalg + (size_t)NTOK * 128;         // [NTOK][128]
    float* gateg = readw + (size_t)NTOK * 128;         // [NTOK]
    float* qwW   = gateg + NTOK;                       // [128][1024] cat(Wq,Wwk)
    // ws usage ~ 25.8 MB

    // split-K partials live in d_out's y region (overwritten later by y-GEMM)
    float* part  = y_out;                              // [2][NTOK][128] = 16 MB < 67 MB

    // 0) concat routing weights; seed outputs with pristine memories
    hipMemcpyAsync(qwW,          Wq,  (size_t)DKEY * DMODEL * 4, hipMemcpyDeviceToDevice, stream);
    hipMemcpyAsync(qwW + 65536,  Wwk, (size_t)DKEY * DMODEL * 4, hipMemcpyDeviceToDevice, stream);
    hipMemcpyAsync(K_out, memK, (size_t)nK * 4, hipMemcpyDeviceToDevice, stream);
    hipMemcpyAsync(V_out, memV, (size_t)nV * 4, hipMemcpyDeviceToDevice, stream);
    hipMemcpyAsync(T_out, memT, (size_t)nT * 4, hipMemcpyDeviceToDevice, stream);

    // 1) projections
    gemm_f32_splitk<<<dim3(NTOK / 64, 1, 2), 256, 0, stream>>>(u, qwW, part, NTOK, DMODEL, DMODEL / 2);
    reduce2_kernel<<<(NTOK * 128 / 4 + 255) / 256, 256, 0, stream>>>(part, part + (size_t)NTOK * 128, qw, NTOK * 128 / 4);
    gemm_mfma_n64<<<dim3(NTOK / 128, 2), 256, 0, stream>>>(u, Wv, wvalg, NTOK, DVAL, DMODEL);
    gate_kernel<<<NTOK / 4, 256, 0, stream>>>(u, Wg, bg, gateg);

    // 2) fused routing / gather / score / read / scatter (atomics into d_out)
    route_kernel<<<NTOK / 4, 256, 0, stream>>>(memK, memV, memT, R, Wvsa,
                                               qw, wvalg, gateg,
                                               K_out, V_out, T_out, readw);

    // 3) y = read @ Wo^T (bf16 MFMA)
    gemm_mfma<<<dim3(NTOK / 128, DMODEL / 128), 256, 0, stream>>>(readw, Wo, y_out, NTOK, DMODEL, DVAL);
}